// Round 7
// baseline (4422.919 us; speedup 1.0000x reference)
//
#include <hip/hip_runtime.h>
#include <math.h>

typedef unsigned long long ull;

// LTC liquid scan — batch-amortized GEMM decomposition.
// Grid 256 = 64 batch-tiles x 4 neuron-tiles; block 512 threads, 1 block/CU
// (LDS 143 KB forces it; co-residency => fence-free spin-wait safe).
// W_rec slice [128 n][512 k] in VGPR/AGPR (128 f/thread). W_in [128][256] LDS.
// Cross-block exchange of x via versioned 8-byte mailbox (RELAXED agent
// atomics; 2 slots by jj parity; version match = data valid; overwrite of
// slot jj&1 safe by 4-peer induction: observing a peer's jj-1 implies the
// peer consumed our jj-2 before its barrier).
//
// Round-9: HANG-PROOF variant of the round-5 design. Two consecutive
// "container failed twice" results on the identical source; protocol audits
// find no deadlock mechanism, but to convert any residual hang into a
// VISIBLE outcome the spin now carries a bounded guard (2^16 sweeps, ~ms):
// healthy waits are a few sweeps; on guard expiry the thread proceeds with
// stale data -> verification fails loudly instead of killing the container.
//
// Round-8 (kept):
//  1. par ELIMINATED: 16 kc-partials per (b,n) live in 16 consecutive lanes
//     -> 4-step __shfl_xor butterfly; removes par LDS traffic (source of the
//     constant 3.1e8 bank conflicts) and the half-idle reduce phase.
//  2. xsh DOUBLE-BUFFERED: ONE __syncthreads per unfold (stage of jj+1 and
//     finish of jj write buffer wp; GEMV of jj reads rp — disjoint).
//  3. LOCAL BYPASS: finish writes own 128-neuron segment straight into the
//     next xsh buffer; staging polls only the 3 remote segments.
// Round-7 (kept): BT=2/NTL=128 partition (4x lower exchange traffic).
// Round-4 (kept): XOR-swizzle at float4 granularity on xsh/iro/wi.

#define NN 512
#define FF 256
#define KK 6
#define TT 256
#define BT 2         // batches per tile
#define NTL 128      // neurons per tile

#define IPITCH 260   // = 65 float4
#define WIPITCH 260  // = 65 float4
#define XBUF (BT * NN)   // 1024 floats per x buffer

#define DOT4(a, v) ((a).x * (v).x + (a).y * (v).y + (a).z * (v).z + (a).w * (v).w)

__global__ __launch_bounds__(512, 2) void liquid_kernel(
    const float* __restrict__ I,     // [B][T][F]
    const float* __restrict__ DT,    // [B][T]
    const float* __restrict__ Wrec,  // [N][N]
    const float* __restrict__ Win,   // [N][F]
    const float* __restrict__ bv, const float* __restrict__ Av,
    const float* __restrict__ tauv,
    ull* __restrict__ mbx,           // [64 bt][2 slot][2 b][512 n] versioned
    float* __restrict__ out)         // [B][T][N]
{
  __shared__ __align__(16) float lds[2 * XBUF + BT * IPITCH + NTL * WIPITCH + 8];
  float* xsh = lds;                    // [2 buf][2 b][512 n], swizzled groups
  float* iro = lds + 2 * XBUF;         // [2][260] input rows, swizzled
  float* wi  = iro + BT * IPITCH;      // [128][260] W_in slice, swizzled
  float* dts = wi + NTL * WIPITCH;     // [2] dt/K per batch

  const int blk = blockIdx.x;
  const int bt  = blk >> 2;          // batch tile (64)
  const int nt  = blk & 3;           // neuron tile (4)
  const int tid = threadIdx.x;
  const int kc  = tid & 15;          // k-chunk (32 k each)
  const int nq  = tid >> 4;          // n-quad (4 n each), 0..31
  const int n0g = nt * NTL;          // global n base of this tile

  // ---- W_rec slice into VGPRs: wv[r][j] = Wrec[n0g+4nq+r][32kc+4j .. +3] ----
  float4 wv[4][8];
  #pragma unroll
  for (int r = 0; r < 4; ++r) {
    const float* wr = Wrec + (size_t)(n0g + nq * 4 + r) * NN + kc * 32;
    #pragma unroll
    for (int j = 0; j < 8; ++j) wv[r][j] = *(const float4*)(wr + 4 * j);
  }
  // ---- W_in slice into LDS (swizzled slot per float4 group) ----
  for (int idx = tid; idx < NTL * FF; idx += 512) {
    const int n = idx >> 8, f = idx & 255;
    const int g = f >> 2, gs = g ^ ((g >> 3) & 7);
    wi[n * WIPITCH + gs * 4 + (f & 3)] = Win[(size_t)(n0g + n) * FF + f];
  }
  // ---- finish-lane params: lane kc<8 owns (b = kc>>2, n = n0g+4nq+(kc&3)) ----
  const int bm = kc >> 2;                           // my batch (kc<8 lanes)
  const int nm = n0g + nq * 4 + (kc & 3);           // my neuron
  float rA = 0.f, rIT = 0.f, rB = 0.f;
  int swn = 0;
  if (kc < 8) {
    rA = Av[nm]; rIT = 1.0f / tauv[nm]; rB = bv[nm];
    const int gg = nm >> 2;
    swn = ((gg ^ ((gg >> 3) & 7)) << 2) | (nm & 3); // swizzled slot of nm
  }
  for (int idx = tid; idx < 2 * XBUF; idx += 512) xsh[idx] = 0.f;  // x0 = 0

  // ---- thread-constant addressing ----
  const int sx  = kc & 7;                           // xsh GEMV read sel
  const int gb  = (kc * 4) ^ ((kc >> 1) & 7);       // wi/iro read slot base
  const float4* iq0 = (const float4*)iro;
  const float4* iq1 = iq0 + 65;
  const float4* wq  = (const float4*)wi + (nq * 4) * 65;
  // staging map: thread covers mailbox entries {2tid, 2tid+1}
  const int stb = tid >> 8;                         // staging batch row
  const int stn = 2 * (tid & 255);                  // local n (even)
  const bool rem = (stn < n0g) || (stn >= n0g + NTL);   // remote segment?
  const int stg = stn >> 2;
  const int sts = ((stg ^ ((stg >> 3) & 7)) << 2) | (stn & 3);
  __syncthreads();

  int jj = 0;
  #pragma unroll 1
  for (int t = 0; t < TT; ++t) {
    // ---- stage input rows (swizzled) + dt ----
    if (tid < 128) {
      const int b = tid >> 6, f4 = tid & 63;
      const int gsi = f4 ^ ((f4 >> 3) & 7);
      ((float4*)iro)[b * 65 + gsi] =
          *(const float4*)&I[((size_t)(bt * BT + b) * TT + t) * FF + f4 * 4];
    }
    if (tid < BT) dts[tid] = DT[(size_t)(bt * BT + tid) * TT + t] * (1.0f / KK);
    __syncthreads();

    // ---- input GEMV + butterfly -> rInp, dtk in registers (kc<8 lanes) ----
    float rInp = 0.f, dtk = 0.f;
    {
      float ai[8] = {0.f, 0.f, 0.f, 0.f, 0.f, 0.f, 0.f, 0.f};
      #pragma unroll
      for (int j2 = 0; j2 < 4; ++j2) {
        const int gg = gb ^ j2;
        float4 w0 = wq[0 * 65 + gg];
        float4 w1 = wq[1 * 65 + gg];
        float4 w2 = wq[2 * 65 + gg];
        float4 w3 = wq[3 * 65 + gg];
        float4 xa = iq0[gg];
        float4 xb = iq1[gg];
        ai[0] += DOT4(w0, xa); ai[1] += DOT4(w1, xa);
        ai[2] += DOT4(w2, xa); ai[3] += DOT4(w3, xa);
        ai[4] += DOT4(w0, xb); ai[5] += DOT4(w1, xb);
        ai[6] += DOT4(w2, xb); ai[7] += DOT4(w3, xb);
      }
      #pragma unroll
      for (int s = 1; s <= 8; s <<= 1) {
        #pragma unroll
        for (int i = 0; i < 8; ++i) ai[i] += __shfl_xor(ai[i], s);
      }
      if (kc < 8) {
        float a0 = (kc & 1) ? ai[1] : ai[0];
        float a1 = (kc & 1) ? ai[3] : ai[2];
        float a2 = (kc & 1) ? ai[5] : ai[4];
        float a3 = (kc & 1) ? ai[7] : ai[6];
        float b0 = (kc & 2) ? a1 : a0;
        float b1 = (kc & 2) ? a3 : a2;
        rInp = rB + ((kc & 4) ? b1 : b0);
        dtk = dts[bm];
      }
    }

    // ---- K unfolds: ONE barrier each ----
    #pragma unroll 1
    for (int kk = 0; kk < KK; ++kk) {
      ++jj;  // producing x_jj; consuming x_{jj-1}
      const int rp = (jj - 1) & 1;   // read buffer / consumed slot parity
      const int wp = jj & 1;         // write buffer / produced slot parity

      // stage remote segments of x_{jj-1} (local 128 already written by
      // finish of jj-1 via the bypass; jj==1: x0=0 pre-zeroed)
      if (jj > 1 && rem) {
        const ull* p = mbx + (((size_t)bt * 2 + rp) << 10) + 2 * tid;
        const unsigned want = (unsigned)(jj - 1);
        ull v0 = __hip_atomic_load(p,     __ATOMIC_RELAXED, __HIP_MEMORY_SCOPE_AGENT);
        ull v1 = __hip_atomic_load(p + 1, __ATOMIC_RELAXED, __HIP_MEMORY_SCOPE_AGENT);
        int guard = 1 << 16;   // hang-proof: healthy waits are a few sweeps
        while (((unsigned)(v0 >> 32) != want || (unsigned)(v1 >> 32) != want)
               && --guard) {
          __builtin_amdgcn_s_sleep(1);
          if ((unsigned)(v0 >> 32) != want)
            v0 = __hip_atomic_load(p,     __ATOMIC_RELAXED, __HIP_MEMORY_SCOPE_AGENT);
          if ((unsigned)(v1 >> 32) != want)
            v1 = __hip_atomic_load(p + 1, __ATOMIC_RELAXED, __HIP_MEMORY_SCOPE_AGENT);
        }
        float* d = xsh + rp * XBUF + stb * NN;
        d[sts]     = __uint_as_float((unsigned)v0);
        d[sts + 1] = __uint_as_float((unsigned)v1);
      }
      __syncthreads();   // xsh[rp] complete (stage remote + prior finish local)

      // GEMV from xsh[rp]: slot (j ^ sx) holds logical group j
      float acc[8] = {0.f, 0.f, 0.f, 0.f, 0.f, 0.f, 0.f, 0.f};
      {
        const float4* x0 = (const float4*)xsh + rp * (XBUF / 4) + kc * 8;
        const float4* x1 = x0 + 128;
        #pragma unroll
        for (int j = 0; j < 8; ++j) {
          float4 xv = x0[j ^ sx];
          acc[0] += DOT4(wv[0][j], xv); acc[1] += DOT4(wv[1][j], xv);
          acc[2] += DOT4(wv[2][j], xv); acc[3] += DOT4(wv[3][j], xv);
        }
        #pragma unroll
        for (int j = 0; j < 8; ++j) {
          float4 xv = x1[j ^ sx];
          acc[4] += DOT4(wv[0][j], xv); acc[5] += DOT4(wv[1][j], xv);
          acc[6] += DOT4(wv[2][j], xv); acc[7] += DOT4(wv[3][j], xv);
        }
      }
      // butterfly over the 16-lane kc group
      #pragma unroll
      for (int s = 1; s <= 8; s <<= 1) {
        #pragma unroll
        for (int i = 0; i < 8; ++i) acc[i] += __shfl_xor(acc[i], s);
      }
      // finish: lanes kc<8 own (bm, nm)
      if (kc < 8) {
        float a0 = (kc & 1) ? acc[1] : acc[0];
        float a1 = (kc & 1) ? acc[3] : acc[2];
        float a2 = (kc & 1) ? acc[5] : acc[4];
        float a3 = (kc & 1) ? acc[7] : acc[6];
        float b0 = (kc & 2) ? a1 : a0;
        float b1 = (kc & 2) ? a3 : a2;
        float arg = rInp + ((kc & 4) ? b1 : b0);
        float f   = tanhf(arg);
        float xo  = xsh[rp * XBUF + bm * NN + swn];
        float xn  = fmaf(dtk * f, rA, xo) / fmaf(dtk, rIT + f, 1.0f);
        xsh[wp * XBUF + bm * NN + swn] = xn;        // local bypass
        ull w = ((ull)(unsigned)jj << 32) | (ull)__float_as_uint(xn);
        __hip_atomic_store(mbx + (((size_t)bt * 2 + wp) << 10) + bm * NN + nm,
                           w, __ATOMIC_RELAXED, __HIP_MEMORY_SCOPE_AGENT);
        if (kk == KK - 1)
          out[((size_t)(bt * BT + bm) * TT + t) * NN + nm] = xn;
      }
      // no trailing barrier: next stage writes buffer wp (disjoint from rp
      // reads); next unfold's single barrier orders everything.
    }
  }
}

extern "C" void kernel_launch(void* const* d_in, const int* in_sizes, int n_in,
                              void* d_out, int out_size, void* d_ws, size_t ws_size,
                              hipStream_t stream) {
  const float* I    = (const float*)d_in[0];
  const float* DT   = (const float*)d_in[1];
  const float* Wrec = (const float*)d_in[2];
  const float* Win  = (const float*)d_in[3];
  const float* bv   = (const float*)d_in[4];
  const float* Av   = (const float*)d_in[5];
  const float* tauv = (const float*)d_in[6];
  float* out = (float*)d_out;
  ull* mbx = (ull*)d_ws;  // 64*2*2*512*8 B = 1 MB

  liquid_kernel<<<256, 512, 0, stream>>>(I, DT, Wrec, Win, bv, Av, tauv, mbx, out);
}

// Round 8
// 3634.298 us; speedup vs baseline: 1.2170x; 1.2170x over previous
//
#include <hip/hip_runtime.h>
#include <math.h>

typedef unsigned long long ull;

// LTC liquid scan — batch-amortized GEMM decomposition.
// Round-10: REVERT to the round-4 structure (best verified: 3474 us) and
// graft ONLY the locally-proven win from round 7: the LOCAL BYPASS.
//   - finish threads (tid<256) write their own (b, n) state directly into
//     xsh after reading xo (same thread, same slot, after the post-GEMV
//     barrier -> race-free in the 3-barrier structure);
//   - staging then polls only the 3 REMOTE segments (rem mask), removing
//     25% of agent-scope poll traffic AND the block's dependency on its own
//     publish round-trip. Round 7 confirmed the FETCH signature of this
//     mechanism (1.64e6 -> 1.25e6 KB).
// Round-7 lessons encoded: the shfl_xor butterfly REGRESSED (dependent
// 32-op ds_bpermute chain slower than the par LDS reduce) and par is NOT
// the main bank-conflict source (3.1e8 -> 2.64e8 only) — both reverted.
// Spin keeps a bounded guard (2^16 sweeps): a hang becomes passed:false,
// not a dead container.
// Round-7 partition (kept): BT=2/NTL=128, grid 256 = 64 bt x 4 nt.
// Round-6 (kept): batched re-poll sweeps. Round-4 (kept): XOR-swizzle.

#define NN 512
#define FF 256
#define KK 6
#define TT 256
#define BT 2         // batches per tile
#define NTL 128      // neurons per tile

#define XROW 512     // xsh row pitch (dwords); conflicts handled by swizzle
#define IPITCH 260   // = 65 float4
#define WIPITCH 260  // = 65 float4
#define PPITCH 17

#define DOT4(a, v) ((a).x * (v).x + (a).y * (v).y + (a).z * (v).z + (a).w * (v).w)

__global__ __launch_bounds__(512, 2) void liquid_kernel(
    const float* __restrict__ I,     // [B][T][F]
    const float* __restrict__ DT,    // [B][T]
    const float* __restrict__ Wrec,  // [N][N]
    const float* __restrict__ Win,   // [N][F]
    const float* __restrict__ bv, const float* __restrict__ Av,
    const float* __restrict__ tauv,
    ull* __restrict__ mbx,           // [64 bt][2 slot][2 b][512 n] versioned
    float* __restrict__ out)         // [B][T][N]
{
  __shared__ __align__(16) float lds[39178];  // 153.0 KB -> 1 block/CU
  float* xsh = lds;                   // [2][512]  x_{jj-1}, swizzled f4 groups
  float* iro = lds + BT * XROW;       // [2][260]  input rows, swizzled
  float* wi  = iro + BT * IPITCH;     // [128][260] W_in slice, swizzled
  float* par = wi + NTL * WIPITCH;    // [256][17] k-chunk partials
  float* dts = par + 256 * PPITCH;    // [2] dt/K per batch

  const int blk = blockIdx.x;
  const int bt  = blk >> 2;          // batch tile (64)
  const int nt  = blk & 3;           // neuron tile (4)
  const int tid = threadIdx.x;
  const int kc  = tid & 15;          // k-chunk (32 k each)
  const int nq  = tid >> 4;          // n-quad (4 n each), 0..31
  const int n0g = nt * NTL;          // global n base of this tile

  // ---- W_rec slice into VGPRs: wv[r][j] = Wrec[n0g+4nq+r][32kc+4j .. +3] ----
  float4 wv[4][8];
  #pragma unroll
  for (int r = 0; r < 4; ++r) {
    const float* wr = Wrec + (size_t)(n0g + nq * 4 + r) * NN + kc * 32;
    #pragma unroll
    for (int j = 0; j < 8; ++j) wv[r][j] = *(const float4*)(wr + 4 * j);
  }
  // ---- W_in slice into LDS (swizzled slot per float4 group) ----
  for (int idx = tid; idx < NTL * FF; idx += 512) {
    const int n = idx >> 8, f = idx & 255;
    const int g = f >> 2, gs = g ^ ((g >> 3) & 7);
    wi[n * WIPITCH + gs * 4 + (f & 3)] = Win[(size_t)(n0g + n) * FF + f];
  }
  // ---- per-(b,n) params + swizzled xo index for reduction threads ----
  float rA = 0.f, rIT = 0.f, rB = 0.f;
  int swn = 0;
  if (tid < 256) {
    const int rn = tid & 127;                       // local neuron
    const int n = n0g + rn;
    rA = Av[n]; rIT = 1.0f / tauv[n]; rB = bv[n];
    const int gg = n >> 2;                          // global f4 group
    swn = ((gg ^ ((gg >> 3) & 7)) << 2) | (n & 3);
  }
  for (int idx = tid; idx < BT * XROW; idx += 512) xsh[idx] = 0.f;  // x0=0

  // ---- thread-constant swizzled addressing (hoisted out of the t-loop) ----
  const int sx  = kc & 7;                           // xsh GEMV read sel
  const int gb  = (kc * 4) ^ ((kc >> 1) & 7);       // wi/iro read slot base
  const float4* xq0 = (const float4*)xsh + kc * 8;  // batch 0
  const float4* xq1 = xq0 + 128;                    // batch 1
  const float4* iq0 = (const float4*)iro;
  const float4* iq1 = iq0 + 65;
  const float4* wq  = (const float4*)wi + (nq * 4) * 65;
  // stage: thread handles mailbox entries {2tid, 2tid+1} -> (b, n, n+1)
  const int stb = tid >> 8;                         // staging batch row
  const int stn = 2 * (tid & 255);                  // global n (even)
  const bool rem = (stn < n0g) || (stn >= n0g + NTL);   // remote segment?
  const int stg = stn >> 2;                         // logical f4 group
  float* stw = xsh + stb * XROW + ((stg ^ ((stg >> 3) & 7)) << 2) + (stn & 3);
  __syncthreads();

  int jj = 0;
  #pragma unroll 1
  for (int t = 0; t < TT; ++t) {
    // ---- stage input rows (swizzled) + dt ----
    if (tid < 2 * 64) {
      const int b = tid >> 6, f4 = tid & 63;
      const int gsi = f4 ^ ((f4 >> 3) & 7);
      ((float4*)iro)[b * 65 + gsi] =
          *(const float4*)&I[((size_t)(bt * BT + b) * TT + t) * FF + f4 * 4];
    }
    if (tid < BT) dts[tid] = DT[(size_t)(bt * BT + tid) * TT + t] * (1.0f / KK);
    __syncthreads();

    // ---- input GEMV partials: inp[b][n] over f in [16kc,16kc+16) ----
    {
      float ai0[4] = {0.f, 0.f, 0.f, 0.f}, ai1[4] = {0.f, 0.f, 0.f, 0.f};
      #pragma unroll
      for (int j2 = 0; j2 < 4; ++j2) {
        const int gg = gb ^ j2;                     // swizzled slot
        float4 w0 = wq[0 * 65 + gg];
        float4 w1 = wq[1 * 65 + gg];
        float4 w2 = wq[2 * 65 + gg];
        float4 w3 = wq[3 * 65 + gg];
        float4 xa = iq0[gg];
        float4 xb = iq1[gg];
        ai0[0] += DOT4(w0, xa); ai0[1] += DOT4(w1, xa);
        ai0[2] += DOT4(w2, xa); ai0[3] += DOT4(w3, xa);
        ai1[0] += DOT4(w0, xb); ai1[1] += DOT4(w1, xb);
        ai1[2] += DOT4(w2, xb); ai1[3] += DOT4(w3, xb);
      }
      #pragma unroll
      for (int r = 0; r < 4; ++r) {
        par[(0 * NTL + nq * 4 + r) * PPITCH + kc] = ai0[r];
        par[(1 * NTL + nq * 4 + r) * PPITCH + kc] = ai1[r];
      }
    }
    __syncthreads();
    float rInp = 0.f;
    if (tid < 256) {
      float s = rB;
      #pragma unroll
      for (int c = 0; c < 16; ++c) s += par[tid * PPITCH + c];
      rInp = s;
    }
    __syncthreads();  // par free for unfold reuse

    // ---- K unfolds ----
    #pragma unroll 1
    for (int kk = 0; kk < KK; ++kk) {
      ++jj;  // producing x_jj; consuming x_{jj-1}

      // stage REMOTE segments of x_{jj-1} from mailbox (local 128 already
      // written by the previous finish via the bypass; jj==1: x0=0 in xsh)
      if (jj > 1 && rem) {
        const ull* src = mbx + (((size_t)bt * 2 + ((jj - 1) & 1)) << 10);
        const ull* p = src + 2 * tid;
        const unsigned want = (unsigned)(jj - 1);
        ull v0 = __hip_atomic_load(p,     __ATOMIC_RELAXED, __HIP_MEMORY_SCOPE_AGENT);
        ull v1 = __hip_atomic_load(p + 1, __ATOMIC_RELAXED, __HIP_MEMORY_SCOPE_AGENT);
        int guard = 1 << 16;   // hang-proof: healthy waits are a few sweeps
        while (((unsigned)(v0 >> 32) != want || (unsigned)(v1 >> 32) != want)
               && --guard) {
          __builtin_amdgcn_s_sleep(1);
          if ((unsigned)(v0 >> 32) != want)
            v0 = __hip_atomic_load(p,     __ATOMIC_RELAXED, __HIP_MEMORY_SCOPE_AGENT);
          if ((unsigned)(v1 >> 32) != want)
            v1 = __hip_atomic_load(p + 1, __ATOMIC_RELAXED, __HIP_MEMORY_SCOPE_AGENT);
        }
        stw[0] = __uint_as_float((unsigned)v0);
        stw[1] = __uint_as_float((unsigned)v1);
      }
      __syncthreads();

      // GEMV: acc[b][n] partial over k in [32kc, 32kc+32), W from VGPRs.
      // slot (j ^ sx) holds logical group j -> pairs with wv[r][j].
      {
        float acc0[4] = {0.f, 0.f, 0.f, 0.f}, acc1[4] = {0.f, 0.f, 0.f, 0.f};
        #pragma unroll
        for (int j = 0; j < 8; ++j) {
          float4 xv = xq0[j ^ sx];
          acc0[0] += DOT4(wv[0][j], xv); acc0[1] += DOT4(wv[1][j], xv);
          acc0[2] += DOT4(wv[2][j], xv); acc0[3] += DOT4(wv[3][j], xv);
        }
        #pragma unroll
        for (int j = 0; j < 8; ++j) {
          float4 xv = xq1[j ^ sx];
          acc1[0] += DOT4(wv[0][j], xv); acc1[1] += DOT4(wv[1][j], xv);
          acc1[2] += DOT4(wv[2][j], xv); acc1[3] += DOT4(wv[3][j], xv);
        }
        #pragma unroll
        for (int r = 0; r < 4; ++r) {
          par[(0 * NTL + nq * 4 + r) * PPITCH + kc] = acc0[r];
          par[(1 * NTL + nq * 4 + r) * PPITCH + kc] = acc1[r];
        }
      }
      __syncthreads();

      // reduce + nonlinearity + bypass + publish (+ output on last unfold)
      if (tid < 256) {
        float arg = rInp;
        #pragma unroll
        for (int c = 0; c < 16; ++c) arg += par[tid * PPITCH + c];
        const int rb = tid >> 7, rn = tid & 127;
        float f   = tanhf(arg);
        float dtk = dts[rb];
        float xo  = xsh[rb * XROW + swn];
        float xn  = fmaf(dtk * f, rA, xo) / fmaf(dtk, rIT + f, 1.0f);
        xsh[rb * XROW + swn] = xn;                  // LOCAL BYPASS (own slot)
        ull w = ((ull)(unsigned)jj << 32) | (ull)__float_as_uint(xn);
        __hip_atomic_store(mbx + (((size_t)bt * 2 + (jj & 1)) << 10) + rb * NN + n0g + rn,
                           w, __ATOMIC_RELAXED, __HIP_MEMORY_SCOPE_AGENT);
        if (kk == KK - 1)
          out[((size_t)(bt * BT + rb) * TT + t) * NN + n0g + rn] = xn;
      }
      __syncthreads();  // xsh/par reads done before next stage overwrites
    }
  }
}

extern "C" void kernel_launch(void* const* d_in, const int* in_sizes, int n_in,
                              void* d_out, int out_size, void* d_ws, size_t ws_size,
                              hipStream_t stream) {
  const float* I    = (const float*)d_in[0];
  const float* DT   = (const float*)d_in[1];
  const float* Wrec = (const float*)d_in[2];
  const float* Win  = (const float*)d_in[3];
  const float* bv   = (const float*)d_in[4];
  const float* Av   = (const float*)d_in[5];
  const float* tauv = (const float*)d_in[6];
  float* out = (float*)d_out;
  ull* mbx = (ull*)d_ws;  // 64*2*2*512*8 B = 1 MB

  liquid_kernel<<<256, 512, 0, stream>>>(I, DT, Wrec, Win, bv, Av, tauv, mbx, out);
}